// Round 12
// baseline (252.028 us; speedup 1.0000x reference)
//
#include <hip/hip_runtime.h>

// WordAttention: B=8, S=2048, D_IN=D_H=512, fp32 in/out.
// R18 = R17 (233.8us) with attn re-tiled for 2 BLOCKS/CU (occupancy play).
// R17 analysis: attn 119us = 2230 cy/phase vs ~1000 cy LDS demand -> ~50%
// exposed barrier/vmcnt stall at 1 block/CU (113KB LDS). Fix: QBLK 64->32,
// KVBLK 128->64 -> LDS 52.5KB, grid 512 -> 2 blocks/CU; a co-resident
// block computes through the other's barrier stalls (m97-style implicit
// overlap). launch_bounds(512,4) pins VGPR<=128 (demand ~100: qf 32,
// oacc 32, sacc 4). Engine unchanged (proven R15 2-barrier ping-pong,
// counted vmcnt); unit sizes halved (16KB, 2 loads/thread, vmcnt(2)).
// V re-tiled to 16KB units [b][s/32][dhalf][256d][32k], same XOR swizzle
// (byte ^= ((dloc>>1)&7)<<4; read-side const still ((fm>>1)&7)<<4 since
// d-base is a multiple of 16). All frag reads re-derived 2-way (free).
// Numerics unchanged (verified R8-R17): unnormalized p=exp(s) bf16
// (|s|<~45<<88), no online max; rowsum shuffle+LDS reduce; normalize last.

typedef __attribute__((ext_vector_type(8))) _Float16 f16x8;
typedef __attribute__((ext_vector_type(8))) short bf16x8;
typedef __attribute__((ext_vector_type(4))) float f32x4;

__device__ __forceinline__ unsigned short f2h(float f) {
  _Float16 h = (_Float16)f;
  return *(unsigned short*)&h;
}
__device__ __forceinline__ unsigned short f2bf(float f) {
  unsigned int u = __float_as_uint(f);
  unsigned int r = (u + 0x7fffu + ((u >> 16) & 1u)) >> 16;
  return (unsigned short)r;
}
__device__ __forceinline__ float bf2f(unsigned short h) {
  return __uint_as_float(((unsigned int)h) << 16);
}

__device__ __forceinline__ void load_lds16(const void* g, void* l) {
  __builtin_amdgcn_global_load_lds(
      (const __attribute__((address_space(1))) unsigned int*)g,
      (__attribute__((address_space(3))) unsigned int*)l, 16, 0, 0);
}

// ---- x fp32 -> fp16 ----
__global__ __launch_bounds__(256) void convx_kernel(const float* __restrict__ x,
                                                    unsigned short* __restrict__ xh) {
  int i = blockIdx.x * 256 + threadIdx.x;
  float4 v = ((const float4*)x)[i];
  union { unsigned short h[4]; short4 s4; } u;
  u.h[0] = f2h(v.x); u.h[1] = f2h(v.y); u.h[2] = f2h(v.z); u.h[3] = f2h(v.w);
  ((short4*)xh)[i] = u.s4;
}

// ---- W [d][h] fp32 -> Wt [h][d] fp16; z = 0,1,2 selects Wq/Wk/Wv ----
__global__ __launch_bounds__(256) void convw_kernel(
    const float* __restrict__ W0, const float* __restrict__ W1,
    const float* __restrict__ W2, unsigned short* __restrict__ Wt) {
  const float* W = (blockIdx.z == 0) ? W0 : (blockIdx.z == 1) ? W1 : W2;
  unsigned short* t = Wt + (size_t)blockIdx.z * 512 * 512;
  __shared__ float tile[32][33];
  int tx = threadIdx.x, ty = threadIdx.y;  // 32 x 8
  int h0 = blockIdx.x * 32, d0 = blockIdx.y * 32;
  for (int i = ty; i < 32; i += 8) tile[i][tx] = W[(long)(d0 + i) * 512 + h0 + tx];
  __syncthreads();
  for (int i = ty; i < 32; i += 8)
    t[(long)(h0 + i) * 512 + d0 + tx] = f2h(tile[tx][i]);
}

// ---- fused QKV projection: [16384,512] x [512,1536]^T + bias.
//      cols 0..511 -> Qo fp16; 512..1023 -> Ko fp16;
//      1024..1535 -> V tiled+swizzled bf16: 16KB unit = (b, s/32, d>>8);
//      within: L = (d&255)*64 + (s%32)*2, stored at L ^ ((d>>1)&7)<<4.
// R17 engine: ping-pong staging + counted vmcnt.
__global__ __launch_bounds__(256) void gemm_qkv_kernel(
    const unsigned short* __restrict__ A,   // xh [16384][512] fp16
    const unsigned short* __restrict__ Bt,  // Wt [1536][512] fp16
    unsigned short* __restrict__ Qo, unsigned short* __restrict__ Ko,
    unsigned short* __restrict__ VTo,
    const float* __restrict__ bq, const float* __restrict__ bk,
    const float* __restrict__ bv) {
  __shared__ alignas(16) unsigned short As[2][4096];  // 2 x 8KB ping-pong
  __shared__ alignas(16) unsigned short Bs[2][4096];
  const int t = threadIdx.x;
  const long long bm = (long long)blockIdx.x * 128;
  const long long bn = (long long)blockIdx.y * 128;

  const int ar = t >> 2;
  const int ac = (t & 3) * 8;

  f32x4 acc[4][4];
#pragma unroll
  for (int i = 0; i < 4; i++)
#pragma unroll
    for (int j = 0; j < 4; j++) acc[i][j] = {0.f, 0.f, 0.f, 0.f};

  const int lane = t & 63;
  const int wave = t >> 6;
  const int wm = (wave & 1) * 64;
  const int wn = (wave >> 1) * 64;
  const int fm = lane & 15;
  const int k8 = (lane >> 4) * 8;

  // prologue: step 0 into buf 0 (4 loads in flight)
#pragma unroll
  for (int r = 0; r < 2; r++)
    load_lds16(A + (bm + r * 64 + ar) * 512 + ac, &As[0][r * 2048 + t * 8]);
#pragma unroll
  for (int r = 0; r < 2; r++)
    load_lds16(Bt + (bn + r * 64 + ar) * 512 + ac, &Bs[0][r * 2048 + t * 8]);

  for (int ktt = 0; ktt < 16; ++ktt) {
    const int cur = ktt & 1;
    const int nxt = cur ^ 1;
    if (ktt < 15) {
      const int kc = (ktt + 1) * 32;
#pragma unroll
      for (int r = 0; r < 2; r++)
        load_lds16(A + (bm + r * 64 + ar) * 512 + kc + ac, &As[nxt][r * 2048 + t * 8]);
#pragma unroll
      for (int r = 0; r < 2; r++)
        load_lds16(Bt + (bn + r * 64 + ar) * 512 + kc + ac, &Bs[nxt][r * 2048 + t * 8]);
      asm volatile("s_waitcnt vmcnt(4)" ::: "memory");  // cur landed, nxt in flight
    } else {
      asm volatile("s_waitcnt vmcnt(0)" ::: "memory");
    }
    __builtin_amdgcn_s_barrier();
    __builtin_amdgcn_sched_barrier(0);

    f16x8 af[4], bfr[4];
#pragma unroll
    for (int i = 0; i < 4; i++)
      af[i] = *(const f16x8*)&As[cur][(wm + i * 16 + fm) * 32 + k8];
#pragma unroll
    for (int j = 0; j < 4; j++)
      bfr[j] = *(const f16x8*)&Bs[cur][(wn + j * 16 + fm) * 32 + k8];
    __builtin_amdgcn_s_setprio(1);
#pragma unroll
    for (int i = 0; i < 4; i++)
#pragma unroll
      for (int j = 0; j < 4; j++)
        acc[i][j] = __builtin_amdgcn_mfma_f32_16x16x32_f16(af[i], bfr[j], acc[i][j], 0, 0, 0);
    __builtin_amdgcn_s_setprio(0);
    asm volatile("s_waitcnt lgkmcnt(0)" ::: "memory");  // my frag reads done
    __builtin_amdgcn_s_barrier();                        // buf free for overwrite
  }

  const int crow = (lane >> 4) * 4;  // C/D: col=lane&15, row=(lane>>4)*4+reg
  const int ccol = lane & 15;
#pragma unroll
  for (int j = 0; j < 4; j++) {
    const long long col = bn + wn + j * 16 + ccol;
    float bias = (col < 512) ? bq[col] : (col < 1024) ? bk[col - 512] : bv[col - 1024];
#pragma unroll
    for (int i = 0; i < 4; i++) {
      const long long row0 = bm + wm + i * 16 + crow;
      if (col >= 1024) {
        const long long b = row0 >> 11;
        const long long s = row0 & 2047;
        const long long dcol = col - 1024;
        union { unsigned short h[4]; short4 s4; } u;
#pragma unroll
        for (int r = 0; r < 4; r++) u.h[r] = f2bf(acc[i][j][r] + bias);  // V -> bf16
        // 16KB V unit = (b, s/32, d>>8); L = (d&255)*64 + (s&31)*2, XOR'd.
        const long long unit = b * 128 + (s >> 5) * 2 + (dcol >> 8);
        const int L = (((int)dcol & 255) * 64 + (int)(s & 31) * 2) ^ ((((int)dcol >> 1) & 7) << 4);
        *(short4*)((char*)VTo + unit * 16384 + L) = u.s4;
      } else {
        unsigned short* dst = (col < 512) ? (Qo + row0 * 512 + col)
                                          : (Ko + row0 * 512 + (col - 512));
#pragma unroll
        for (int r = 0; r < 4; r++) dst[(size_t)r * 512] = f2h(acc[i][j][r] + bias);
      }
    }
  }
}

// ---- fused attention: out[b][q][d] = (sum_k exp(QK^T) V) / rowsum.
// grid 512 (b=bid&7, q-tile=bid>>3: 32 q-rows), 512 threads (8 waves),
// 2 blocks/CU (LDS 52.5KB, VGPR<=128 via launch_bounds(512,4)).
// Wave w: qh=w&1 (16-q half), kg=w>>1 (16-k group in QKT / 64-d slice in PV).
// Per kt (KVBLK=64): u0..3 QKT on K units [64k][128d] (16KB);
// u3 tail exp->Ps[32q][64k]; u4..7 PV on V units [256d][32k] (16KB):
// u4=(kh0,dh0) u5=(kh0,dh1) u6=(kh1,dh0) u7=(kh1,dh1).
__global__ __launch_bounds__(512, 4) void attn_fused_kernel(
    const unsigned short* __restrict__ Qg,  // [8][2048][512] fp16
    const unsigned short* __restrict__ Kg,  // [8][2048][512] fp16
    const unsigned short* __restrict__ Vt,  // [8][128] x 16KB swizzled V units
    float* __restrict__ out) {              // [8][2048][512] fp32
  __shared__ alignas(16) unsigned short SB[2][8192];  // 2x16KB stage ping-pong
  __shared__ alignas(16) unsigned short Qh[8192];     // Q high-d [32q][256d] swz
  __shared__ alignas(16) unsigned short Ps[2048];     // P [32q][64k] bf16 swz
  __shared__ float rsw[4][32];

  const int t = threadIdx.x;
  const int lane = t & 63;
  const int w = t >> 6;
  const int fm = lane & 15;
  const int g = lane >> 4;
  const int qh = w & 1;
  const int kg = w >> 1;
  const int b = blockIdx.x & 7;
  const int q0 = (blockIdx.x >> 3) << 5;

  const unsigned short* Qb = Qg + ((size_t)b * 2048 + q0) * 512;
  const unsigned short* Kb = Kg + (size_t)b * 2048 * 512;
  const unsigned short* Vb = Vt + (size_t)b * 2048 * 512;  // 128 x 8192 shorts

  // per-thread staging offsets (2 rounds x 512 thr x 16B = 16KB/unit)
  int ksrc[2], qsrc[2]; unsigned int sdst[2];
#pragma unroll
  for (int r = 0; r < 2; ++r) {
    const int L = r * 8192 + t * 16;  // byte offset within a 16KB unit
    sdst[r] = L >> 1;
    const int kr = L >> 8;            // K unit rows (256 B, 64 rows)
    ksrc[r] = kr * 512 + (((L & 255) ^ ((kr & 7) << 4)) >> 1);
    const int qr = L >> 9;            // Q rows (512 B, 32 rows)
    qsrc[r] = qr * 512 + (((L & 511) ^ ((qr & 7) << 4)) >> 1);
  }

  // ---- prologue: stage Qlow -> SB0 (16KB), Qhigh -> Qh; Q-frags to regs ----
#pragma unroll
  for (int r = 0; r < 2; ++r) load_lds16(Qb + qsrc[r], &SB[0][sdst[r]]);
#pragma unroll
  for (int r = 0; r < 2; ++r) load_lds16(Qb + 256 + qsrc[r], &Qh[sdst[r]]);
  asm volatile("s_waitcnt vmcnt(2)" ::: "memory");  // Qlow landed (Qh may fly)
  __builtin_amdgcn_s_barrier();

  const int swz = (fm & 7) << 4;
  const int vswz = ((fm >> 1) & 7) << 4;  // V-read side of the V swizzle
  f16x8 qf[8];  // Q hoist d<256: one q-frag x 8 d-chunks, 32 VGPRs
#pragma unroll
  for (int ds = 0; ds < 8; ++ds)
    qf[ds] = *(const f16x8*)((const char*)SB[0] +
        (qh * 16 + fm) * 512 + ((g * 16 + ds * 64) ^ swz));
  asm volatile("s_waitcnt lgkmcnt(0)" ::: "memory");
  __builtin_amdgcn_s_barrier();
  // stage K-unit0 of kt0 into SB0 (cur of phase 0)
#pragma unroll
  for (int r = 0; r < 2; ++r) load_lds16(Kb + ksrc[r], &SB[0][sdst[r]]);

  f32x4 oacc[8];  // [dh*4 + jj]: wave's 16q x (2 x 64d slices)
#pragma unroll
  for (int jj = 0; jj < 8; ++jj) oacc[jj] = {0.f, 0.f, 0.f, 0.f};
  float psum0 = 0.f;
  f32x4 sacc;

  for (int kt = 0; kt < 32; ++kt) {
    const size_t kbase = (size_t)kt * 32768;  // kt*64*512 elements
#pragma unroll
    for (int u = 0; u < 8; ++u) {
      unsigned short* curb = SB[u & 1];
      unsigned short* nxt = SB[(u & 1) ^ 1];
      // ---- issue next stage unit (1 phase ahead) ----
      if (u < 3) {  // K units 1..3 (d slices)
#pragma unroll
        for (int r = 0; r < 2; ++r)
          load_lds16(Kb + kbase + (u + 1) * 128 + ksrc[r], &nxt[sdst[r]]);
      } else if (u < 7) {  // V units kt*4 .. kt*4+3
        const unsigned short* vs = Vb + (size_t)(kt * 4 + (u - 3)) * 8192;
#pragma unroll
        for (int r = 0; r < 2; ++r) load_lds16(vs + sdst[r], &nxt[sdst[r]]);
      } else if (kt < 31) {  // next kt K unit 0
#pragma unroll
        for (int r = 0; r < 2; ++r)
          load_lds16(Kb + kbase + 32768 + ksrc[r], &nxt[sdst[r]]);
      }
      // ---- counted wait: cur's 2 loads done, nxt's 2 stay in flight ----
      if (kt == 31 && u == 7)
        asm volatile("s_waitcnt vmcnt(0)" ::: "memory");
      else
        asm volatile("s_waitcnt vmcnt(2)" ::: "memory");
      __builtin_amdgcn_s_barrier();
      __builtin_amdgcn_sched_barrier(0);

      __builtin_amdgcn_s_setprio(1);
      if (u < 4) {
        // ---- QKT phase: S^T[k 16-grp][q 32] += K-unit_u x Q(d-slice) ----
        if (u == 0) sacc = {0.f, 0.f, 0.f, 0.f};
#pragma unroll
        for (int s = 0; s < 4; ++s) {
          const f16x8 a0 = *(const f16x8*)((const char*)curb +
              (kg * 16 + fm) * 256 + ((g * 16 + s * 64) ^ swz));
          f16x8 b0;
          if (u < 2) {
            b0 = qf[u * 4 + s];
          } else {
            const int dz = (g * 16 + ((u - 2) * 4 + s) * 64) ^ swz;
            b0 = *(const f16x8*)((const char*)Qh + (qh * 16 + fm) * 512 + dz);
          }
          sacc = __builtin_amdgcn_mfma_f32_16x16x32_f16(a0, b0, sacc, 0, 0, 0);
        }
        if (u == 3) {
          // exp -> bf16 P (swizzled) + rowsum partial
          // S^T frag: col=q=qh*16+fm, row=k=kg*16+g*4+r
          const int q = qh * 16 + fm;
          const int k2 = kg * 32 + g * 8;  // (k-row)*2, r=0
          union { unsigned short h[4]; short4 s4; } uu;
          float sthis = 0.f;
#pragma unroll
          for (int r = 0; r < 4; ++r) {
            const unsigned short pb = f2bf(__expf(sacc[r]));
            uu.h[r] = pb; sthis += bf2f(pb);
          }
          psum0 += sthis;
          *(short4*)((char*)Ps + q * 128 + (k2 ^ swz)) = uu.s4;
        }
      } else {
        // ---- PV phase: unit (kh,dh); wave adds 16q x 64d slice ----
        const int kh = (u - 4) >> 1;
        const int dh = (u - 4) & 1;
        const bf16x8 p0 = *(const bf16x8*)((const char*)Ps +
            (qh * 16 + fm) * 128 + ((kh * 64 + g * 16) ^ swz));
#pragma unroll
        for (int jj = 0; jj < 4; ++jj) {
          const bf16x8 vf = *(const bf16x8*)((const char*)curb +
              ((((kg * 64 + jj * 16 + fm) * 64) + g * 16) ^ vswz));
          oacc[dh * 4 + jj] = __builtin_amdgcn_mfma_f32_16x16x32_bf16(p0, vf, oacc[dh * 4 + jj], 0, 0, 0);
        }
      }
      __builtin_amdgcn_s_setprio(0);
      asm volatile("s_waitcnt lgkmcnt(0)" ::: "memory");  // all my LDS reads done
      __builtin_amdgcn_s_barrier();                        // buf free for overwrite
    }
  }

  // ---- rowsum reduce: quads (shuffle) then k-groups (LDS) ----
  psum0 += __shfl_xor(psum0, 16); psum0 += __shfl_xor(psum0, 32);
  if (g == 0) rsw[kg][qh * 16 + fm] = psum0;
  __syncthreads();

  // ---- normalize + store: row q = qh*16+g*4+r, col d = dh*256+kg*64+jj*16+fm
  float* ob = out + ((size_t)b * 2048 + q0) * 512;
  float inv[4];
#pragma unroll
  for (int r = 0; r < 4; ++r) {
    const int q = qh * 16 + g * 4 + r;
    inv[r] = 1.0f / (rsw[0][q] + rsw[1][q] + rsw[2][q] + rsw[3][q]);
  }
#pragma unroll
  for (int dh = 0; dh < 2; ++dh)
#pragma unroll
    for (int jj = 0; jj < 4; ++jj) {
      const int d = dh * 256 + kg * 64 + jj * 16 + fm;
#pragma unroll
      for (int r = 0; r < 4; ++r)
        ob[(size_t)(qh * 16 + g * 4 + r) * 512 + d] = oacc[dh * 4 + jj][r] * inv[r];
    }
}

extern "C" void kernel_launch(void* const* d_in, const int* in_sizes, int n_in,
                              void* d_out, int out_size, void* d_ws, size_t ws_size,
                              hipStream_t stream) {
  const float* x  = (const float*)d_in[0];
  const float* Wq = (const float*)d_in[1];
  const float* bq = (const float*)d_in[2];
  const float* Wk = (const float*)d_in[3];
  const float* bk = (const float*)d_in[4];
  const float* Wv = (const float*)d_in[5];
  const float* bv = (const float*)d_in[6];
  float* out = (float*)d_out;

  const size_t SZ = (size_t)16384 * 512 * 2;  // 16.78 MB (half-prec [16384,512])
  char* p = (char*)d_ws;
  unsigned short* xh = (unsigned short*)p; p += SZ;
  unsigned short* Wt = (unsigned short*)p; p += (size_t)3 * 512 * 512 * 2;
  unsigned short* Qb = (unsigned short*)p; p += SZ;              // fp16 [token][512]
  unsigned short* Kb = (unsigned short*)p; p += SZ;              // fp16 [token][512]
  unsigned short* VT = (unsigned short*)p; p += SZ;              // bf16 swizzled V units (16KB)

  convx_kernel<<<8192, 256, 0, stream>>>(x, xh);
  convw_kernel<<<dim3(16, 16, 3), dim3(32, 8), 0, stream>>>(Wq, Wk, Wv, Wt);
  gemm_qkv_kernel<<<dim3(128, 12), 256, 0, stream>>>(xh, Wt, Qb, Kb, VT, bq, bk, bv);
  attn_fused_kernel<<<512, 512, 0, stream>>>(Qb, Kb, VT, out);
}